// Round 13
// baseline (1715.228 us; speedup 1.0000x reference)
//
#include <hip/hip_runtime.h>

#define NUM_USERS_ 50000
#define NUM_ITEMS_ 100000
#define NN 150000            // NUM_USERS + NUM_ITEMS
#define DD 128
#define NNZ_ 4800000
#define NLAYERS_ 3
#define SUBR (NN / 8)        // 18750 rows per XCD subrange
#define EPSL 32768           // edges per slice for partitioned hist/scatter
#define NSLICE ((NNZ_ + EPSL - 1) / EPSL)   // 147
#define SCANB 1024           // counts per scan block
#define NSCANB ((NN + SCANB - 1) / SCANB)   // 147

// ---------------- CSR build (deterministic, XCD-partitioned atomics) ----------------

__global__ __launch_bounds__(256) void hist_kernel(const int* __restrict__ rows,
                                                   int* __restrict__ counts) {
    int slice = blockIdx.x >> 3;
    int sub   = blockIdx.x & 7;
    int lo = sub * SUBR, hi = lo + SUBR;
    int base = slice * EPSL;
    int stop = base + EPSL; if (stop > NNZ_) stop = NNZ_;
    for (int e = base + threadIdx.x; e < stop; e += 256) {
        int r = rows[e];
        if (r >= lo && r < hi) atomicAdd(&counts[r], 1);
    }
}

// ---- two-level exclusive scan of counts[0..NN) -> row_ptr / cursor ----
__global__ __launch_bounds__(256) void scanA_kernel(const int* __restrict__ counts,
                                                    int* __restrict__ row_ptr,
                                                    int* __restrict__ bsum) {
    __shared__ int part[256];
    int b = blockIdx.x, t = threadIdx.x;
    int base = b * SCANB + t * 4;
    int c[4];
    #pragma unroll
    for (int u = 0; u < 4; ++u) {
        int i = base + u;
        c[u] = (i < NN) ? counts[i] : 0;
    }
    int mysum = c[0] + c[1] + c[2] + c[3];
    part[t] = mysum;
    __syncthreads();
    for (int off = 1; off < 256; off <<= 1) {
        int v = (t >= off) ? part[t - off] : 0;
        __syncthreads();
        part[t] += v;
        __syncthreads();
    }
    int excl = part[t] - mysum;
    #pragma unroll
    for (int u = 0; u < 4; ++u) {
        int i = base + u;
        if (i < NN) row_ptr[i] = excl;
        excl += c[u];
    }
    if (t == 255) bsum[b] = part[255];
}

__global__ __launch_bounds__(256) void scanB_kernel(int* __restrict__ bsum,
                                                    int* __restrict__ total) {
    __shared__ int s[NSCANB];
    int t = threadIdx.x;
    if (t < NSCANB) s[t] = bsum[t];
    __syncthreads();
    if (t == 0) {
        int run = 0;
        for (int i = 0; i < NSCANB; ++i) {
            int v = s[i];
            s[i] = run;
            run += v;
        }
        *total = run;
    }
    __syncthreads();
    if (t < NSCANB) bsum[t] = s[t];
}

__global__ __launch_bounds__(256) void scanC_kernel(int* __restrict__ row_ptr,
                                                    int* __restrict__ cursor,
                                                    const int* __restrict__ bsum,
                                                    const int* __restrict__ total) {
    int b = blockIdx.x, t = threadIdx.x;
    int off = bsum[b];
    int base = b * SCANB + t * 4;
    #pragma unroll
    for (int u = 0; u < 4; ++u) {
        int i = base + u;
        if (i < NN) {
            int v = row_ptr[i] + off;
            row_ptr[i] = v;
            cursor[i]  = v;
        }
    }
    if (b == 0 && t == 0) row_ptr[NN] = *total;
}

// scatter one packed 16B record (e, col, val, 0) per edge into its CSR slot
__global__ __launch_bounds__(256) void scatter_kernel(const int* __restrict__ rows,
                                                      const int* __restrict__ cols,
                                                      const float* __restrict__ vals,
                                                      int* __restrict__ cursor,
                                                      int4* __restrict__ tri) {
    int slice = blockIdx.x >> 3;
    int sub   = blockIdx.x & 7;
    int lo = sub * SUBR, hi = lo + SUBR;
    int base = slice * EPSL;
    int stop = base + EPSL; if (stop > NNZ_) stop = NNZ_;
    for (int e = base + threadIdx.x; e < stop; e += 256) {
        int r = rows[e];
        if (r >= lo && r < hi) {
            int pos = atomicAdd(&cursor[r], 1);
            tri[pos] = make_int4(e, cols[e], __float_as_int(vals[e]), 0);
        }
    }
}

// ---------------- per-row wave bitonic sort by edge index ----------------
__global__ __launch_bounds__(256) void sortrows_kernel(const int* __restrict__ row_ptr,
                                                       int4* __restrict__ tri,
                                                       int2* __restrict__ cpack) {
    int wave = threadIdx.x >> 6;
    int lane = threadIdx.x & 63;
    int row  = blockIdx.x * 4 + wave;
    if (row >= NN) return;
    int beg = row_ptr[row], end = row_ptr[row + 1];
    int deg = end - beg;
    if (deg <= 0) return;

    if (deg <= 128) {
        const int PAD = 0x7fffffff;
        int e0 = PAD, c0 = 0; float v0 = 0.0f;
        int e1 = PAD, c1 = 0; float v1 = 0.0f;
        if (lane < deg) {
            int4 t = tri[beg + lane];
            e0 = t.x; c0 = t.y; v0 = __int_as_float(t.z);
        }
        if (64 + lane < deg) {
            int4 t = tri[beg + 64 + lane];
            e1 = t.x; c1 = t.y; v1 = __int_as_float(t.z);
        }
        #pragma unroll
        for (int k = 2; k <= 128; k <<= 1) {
            #pragma unroll
            for (int j = 64; j > 0; j >>= 1) {
                if (j > (k >> 1)) continue;
                if (j == 64) {
                    if (e0 > e1) {
                        int te = e0; e0 = e1; e1 = te;
                        int tc = c0; c0 = c1; c1 = tc;
                        float tv = v0; v0 = v1; v1 = tv;
                    }
                } else {
                    int   pe = __shfl_xor(e0, j, 64);
                    int   pc = __shfl_xor(c0, j, 64);
                    float pv = __shfl_xor(v0, j, 64);
                    bool tmin0 = ((lane & k) == 0) == ((lane & j) == 0);
                    bool sw0 = tmin0 ? (pe < e0) : (pe > e0);
                    if (sw0) { e0 = pe; c0 = pc; v0 = pv; }
                    int   qe = __shfl_xor(e1, j, 64);
                    int   qc = __shfl_xor(c1, j, 64);
                    float qv = __shfl_xor(v1, j, 64);
                    int i1 = 64 + lane;
                    bool tmin1 = ((i1 & k) == 0) == ((i1 & j) == 0);
                    bool sw1 = tmin1 ? (qe < e1) : (qe > e1);
                    if (sw1) { e1 = qe; c1 = qc; v1 = qv; }
                }
            }
        }
        if (lane < deg)      cpack[beg + lane]      = make_int2(c0, __float_as_int(v0));
        if (64 + lane < deg) cpack[beg + 64 + lane] = make_int2(c1, __float_as_int(v1));
    } else {
        if (lane == 0) {
            for (int i = beg + 1; i < end; ++i) {
                int4 key = tri[i];
                int j = i - 1;
                while (j >= beg && tri[j].x > key.x) { tri[j + 1] = tri[j]; --j; }
                tri[j + 1] = key;
            }
            for (int i = beg; i < end; ++i)
                cpack[i] = make_int2(tri[i].y, tri[i].z);
        }
    }
}

// ---------------- fused SpMM + in-wave npyv norm + noise (+ final combine) ----------------
// One wave per row; lane owns columns [2*lane, 2*lane+1].
// Scalarized edge stream (readfirstlane on beg/end -> s_load edge records,
// SGPR-based gather addressing). Accumulation chain in exact edge order.
// NT policy (r13): ego stores NORMAL (the 2.46 GB/layer-reuse slab must stay
// in L3!); noise NT-load (pure stream); cpack NT-load (38 MB sequential);
// final output NT-store (never re-read). Resident set ego_a+ego_b = 154 MB < L3.

template <int LAYER>
__device__ __forceinline__ float2 gather_row(const float* __restrict__ xa,
                                             const float* __restrict__ xb,
                                             int c, int lane) {
    const float* p;
    if (LAYER == 1)
        p = (c < NUM_USERS_) ? (xa + (size_t)c * DD) : (xb + (size_t)(c - NUM_USERS_) * DD);
    else
        p = xa + (size_t)c * DD;
    return ((const float2*)p)[lane];
}

template <int LAYER>   // 1, 2, 3
__global__ __launch_bounds__(256, 2) void layer_kernel(
    const int* __restrict__ row_ptr, const int2* __restrict__ cpack,
    const float* __restrict__ xa,    // L1: user_emb; L2/L3: gather source slab
    const float* __restrict__ xb,    // L1: item_emb; else unused
    const float* __restrict__ noise_k,
    float* __restrict__ y_out,       // L1/L2: ego out slab; L3: final output
    const float* __restrict__ y1,    // L3: ego after layer 1
    const float* __restrict__ y2) {  // L3: ego after layer 2
    int wave = threadIdx.x >> 6;
    int lane = threadIdx.x & 63;
    int row  = blockIdx.x * 4 + wave;
    if (row >= NN) return;

    // wave-uniform row bounds -> SGPR; everything derived is scalar
    int beg = __builtin_amdgcn_readfirstlane(row_ptr[row]);
    int end = __builtin_amdgcn_readfirstlane(row_ptr[row + 1]);

    float a0 = 0.0f, a1 = 0.0f;
    // batches of 32: scalar edge records + 32 independent SGPR-based gathers
    // in flight; accumulate afterwards in exact edge order (masked tail:
    // v=0 -> a+(+/-0)==a bitwise; accumulator can never be -0).
    for (int j = beg; j < end; j += 32) {
        float2 xv[32];
        float  vv[32];
        #pragma unroll
        for (int u = 0; u < 32; ++u) {
            int jj  = j + u;
            int idx = (jj < end) ? jj : (end - 1);   // uniform
            unsigned long long q = __builtin_nontemporal_load(
                (const unsigned long long*)&cpack[idx]);   // uniform -> s_load
            vv[u] = (jj < end) ? __int_as_float((int)(unsigned)(q >> 32)) : 0.0f;
            xv[u] = gather_row<LAYER>(xa, xb, (int)(unsigned)(q & 0xffffffffull), lane);
        }
        #pragma unroll
        for (int u = 0; u < 32; ++u) {
            a0 = __fadd_rn(a0, __fmul_rn(vv[u], xv[u].x));
            a1 = __fadd_rn(a1, __fmul_rn(vv[u], xv[u].y));
        }
    }

    // noise row (NT load) + in-wave exact npyv pairwise norm:
    // xor32; xor8; xor16; then halving tree xor4, xor2, xor1; final .x+.y.
    unsigned long long nq = __builtin_nontemporal_load(
        (const unsigned long long*)(noise_k + (long long)row * DD) + lane);
    float2 nv = make_float2(__int_as_float((int)(unsigned)(nq & 0xffffffffull)),
                            __int_as_float((int)(unsigned)(nq >> 32)));
    float sx = __fmul_rn(nv.x, nv.x);
    float sy = __fmul_rn(nv.y, nv.y);
    float tx = __fadd_rn(sx, __shfl_xor(sx, 32, 64));
    float ty = __fadd_rn(sy, __shfl_xor(sy, 32, 64));
    tx = __fadd_rn(tx, __shfl_xor(tx, 8, 64));
    ty = __fadd_rn(ty, __shfl_xor(ty, 8, 64));
    tx = __fadd_rn(tx, __shfl_xor(tx, 16, 64));
    ty = __fadd_rn(ty, __shfl_xor(ty, 16, 64));
    tx = __fadd_rn(tx, __shfl_xor(tx, 4, 64));
    ty = __fadd_rn(ty, __shfl_xor(ty, 4, 64));
    tx = __fadd_rn(tx, __shfl_xor(tx, 2, 64));
    ty = __fadd_rn(ty, __shfl_xor(ty, 2, 64));
    tx = __fadd_rn(tx, __shfl_xor(tx, 1, 64));
    ty = __fadd_rn(ty, __shfl_xor(ty, 1, 64));
    float nrm = __fsqrt_rn(__fadd_rn(tx, ty));

    float s0 = (a0 > 0.0f) ? 1.0f : ((a0 < 0.0f) ? -1.0f : 0.0f);
    float s1 = (a1 > 0.0f) ? 1.0f : ((a1 < 0.0f) ? -1.0f : 0.0f);
    // np order: nk = n / nrm;  t = (sign * nk) * 0.2f;  ego = a + t
    float q0 = __fdiv_rn(nv.x, nrm);
    float q1 = __fdiv_rn(nv.y, nrm);
    float t0 = __fmul_rn(__fmul_rn(s0, q0), 0.2f);
    float t1 = __fmul_rn(__fmul_rn(s1, q1), 0.2f);
    float e0 = __fadd_rn(a0, t0);
    float e1 = __fadd_rn(a1, t1);

    if (LAYER < 3) {
        // NORMAL store: this slab is the next layer's gather source (keep in L3)
        ((float2*)(y_out + (long long)row * DD))[lane] = make_float2(e0, e1);
    } else {
        // final = ((e1 + e2) + e3) / 3, identical __fadd_rn/__fdiv_rn chain
        float2 p1 = ((const float2*)(y1 + (long long)row * DD))[lane];
        float2 p2 = ((const float2*)(y2 + (long long)row * DD))[lane];
        float g0 = __fadd_rn(__fadd_rn(p1.x, p2.x), e0);
        float g1 = __fadd_rn(__fadd_rn(p1.y, p2.y), e1);
        float r0 = __fdiv_rn(g0, 3.0f);
        float r1 = __fdiv_rn(g1, 3.0f);
        unsigned long long w =
            ((unsigned long long)(unsigned)__float_as_int(r1) << 32) |
            (unsigned long long)(unsigned)__float_as_int(r0);
        __builtin_nontemporal_store(
            w, (unsigned long long*)(y_out + (long long)row * DD) + lane);
    }
}

extern "C" void kernel_launch(void* const* d_in, const int* in_sizes, int n_in,
                              void* d_out, int out_size, void* d_ws, size_t ws_size,
                              hipStream_t stream) {
    const float* user  = (const float*)d_in[0];
    const float* item  = (const float*)d_in[1];
    const float* vals  = (const float*)d_in[2];
    const float* noise = (const float*)d_in[3];
    const int*   rows  = (const int*)d_in[4];
    const int*   cols  = (const int*)d_in[5];
    float* out = (float*)d_out;

    char* ws = (char*)d_ws;
    size_t off = 0;
    auto alloc = [&](size_t bytes) -> char* {
        char* p = ws + off;
        off = (off + bytes + 255) & ~(size_t)255;
        return p;
    };

    int*   counts  = (int*)  alloc((size_t)NN * 4);
    int*   row_ptr = (int*)  alloc((size_t)(NN + 1) * 4);
    int*   cursor  = (int*)  alloc((size_t)NN * 4);
    int*   bsum    = (int*)  alloc((size_t)NSCANB * 4);
    int*   total   = (int*)  alloc(256);
    int4*  tri     = (int4*) alloc((size_t)NNZ_ * 16);
    int2*  cpack   = (int2*) alloc((size_t)NNZ_ * 8);
    float* ego_a   = (float*)alloc((size_t)NN * DD * 4);
    float* ego_b   = (float*)alloc((size_t)NN * DD * 4);

    hipMemsetAsync(counts, 0, (size_t)NN * 4, stream);

    hist_kernel<<<NSLICE * 8, 256, 0, stream>>>(rows, counts);
    scanA_kernel<<<NSCANB, 256, 0, stream>>>(counts, row_ptr, bsum);
    scanB_kernel<<<1, 256, 0, stream>>>(bsum, total);
    scanC_kernel<<<NSCANB, 256, 0, stream>>>(row_ptr, cursor, bsum, total);
    scatter_kernel<<<NSLICE * 8, 256, 0, stream>>>(rows, cols, vals, cursor, tri);
    sortrows_kernel<<<(NN + 3) / 4, 256, 0, stream>>>(row_ptr, tri, cpack);

    const long long slab = (long long)NN * DD;
    int lgrid = (NN + 3) / 4;
    layer_kernel<1><<<lgrid, 256, 0, stream>>>(row_ptr, cpack, user, item,
                                               noise + 0 * slab, ego_b, nullptr, nullptr);
    layer_kernel<2><<<lgrid, 256, 0, stream>>>(row_ptr, cpack, ego_b, nullptr,
                                               noise + 1 * slab, ego_a, nullptr, nullptr);
    layer_kernel<3><<<lgrid, 256, 0, stream>>>(row_ptr, cpack, ego_a, nullptr,
                                               noise + 2 * slab, out, ego_b, ego_a);
}

// Round 16
// 1704.148 us; speedup vs baseline: 1.0065x; 1.0065x over previous
//
#include <hip/hip_runtime.h>

#define NUM_USERS_ 50000
#define NUM_ITEMS_ 100000
#define NN 150000            // NUM_USERS + NUM_ITEMS
#define DD 128
#define NNZ_ 4800000
#define NLAYERS_ 3
#define SUBR (NN / 8)        // 18750 rows per XCD subrange
#define EPSL 32768           // edges per slice for partitioned hist/scatter
#define NSLICE ((NNZ_ + EPSL - 1) / EPSL)   // 147
#define SCANB 1024           // counts per scan block
#define NSCANB ((NN + SCANB - 1) / SCANB)   // 147

// ---------------- CSR build (deterministic, XCD-partitioned atomics) ----------------
// NOTE (r14 measured): within-row summation ORDER IS LOAD-BEARING. Arbitrary
// order flips a borderline sign (absmax 1.99e-2 vs threshold 6.9e-4). The
// per-row sort by edge index below replicates np.add.at's exact order.

__global__ __launch_bounds__(256) void hist_kernel(const int* __restrict__ rows,
                                                   int* __restrict__ counts) {
    int slice = blockIdx.x >> 3;
    int sub   = blockIdx.x & 7;
    int lo = sub * SUBR, hi = lo + SUBR;
    int base = slice * EPSL;
    int stop = base + EPSL; if (stop > NNZ_) stop = NNZ_;
    for (int e = base + threadIdx.x; e < stop; e += 256) {
        int r = rows[e];
        if (r >= lo && r < hi) atomicAdd(&counts[r], 1);
    }
}

// ---- two-level exclusive scan of counts[0..NN) -> row_ptr / cursor ----
__global__ __launch_bounds__(256) void scanA_kernel(const int* __restrict__ counts,
                                                    int* __restrict__ row_ptr,
                                                    int* __restrict__ bsum) {
    __shared__ int part[256];
    int b = blockIdx.x, t = threadIdx.x;
    int base = b * SCANB + t * 4;
    int c[4];
    #pragma unroll
    for (int u = 0; u < 4; ++u) {
        int i = base + u;
        c[u] = (i < NN) ? counts[i] : 0;
    }
    int mysum = c[0] + c[1] + c[2] + c[3];
    part[t] = mysum;
    __syncthreads();
    for (int off = 1; off < 256; off <<= 1) {
        int v = (t >= off) ? part[t - off] : 0;
        __syncthreads();
        part[t] += v;
        __syncthreads();
    }
    int excl = part[t] - mysum;
    #pragma unroll
    for (int u = 0; u < 4; ++u) {
        int i = base + u;
        if (i < NN) row_ptr[i] = excl;
        excl += c[u];
    }
    if (t == 255) bsum[b] = part[255];
}

__global__ __launch_bounds__(256) void scanB_kernel(int* __restrict__ bsum,
                                                    int* __restrict__ total) {
    __shared__ int s[NSCANB];
    int t = threadIdx.x;
    if (t < NSCANB) s[t] = bsum[t];
    __syncthreads();
    if (t == 0) {
        int run = 0;
        for (int i = 0; i < NSCANB; ++i) {
            int v = s[i];
            s[i] = run;
            run += v;
        }
        *total = run;
    }
    __syncthreads();
    if (t < NSCANB) bsum[t] = s[t];
}

__global__ __launch_bounds__(256) void scanC_kernel(int* __restrict__ row_ptr,
                                                    int* __restrict__ cursor,
                                                    const int* __restrict__ bsum,
                                                    const int* __restrict__ total) {
    int b = blockIdx.x, t = threadIdx.x;
    int off = bsum[b];
    int base = b * SCANB + t * 4;
    #pragma unroll
    for (int u = 0; u < 4; ++u) {
        int i = base + u;
        if (i < NN) {
            int v = row_ptr[i] + off;
            row_ptr[i] = v;
            cursor[i]  = v;
        }
    }
    if (b == 0 && t == 0) row_ptr[NN] = *total;
}

// scatter one packed 16B record (e, col, val, 0) per edge into its CSR slot
// (within-row order arbitrary; fixed by the wave-bitonic sort below).
__global__ __launch_bounds__(256) void scatter_kernel(const int* __restrict__ rows,
                                                      const int* __restrict__ cols,
                                                      const float* __restrict__ vals,
                                                      int* __restrict__ cursor,
                                                      int4* __restrict__ tri) {
    int slice = blockIdx.x >> 3;
    int sub   = blockIdx.x & 7;
    int lo = sub * SUBR, hi = lo + SUBR;
    int base = slice * EPSL;
    int stop = base + EPSL; if (stop > NNZ_) stop = NNZ_;
    for (int e = base + threadIdx.x; e < stop; e += 256) {
        int r = rows[e];
        if (r >= lo && r < hi) {
            int pos = atomicAdd(&cursor[r], 1);
            tri[pos] = make_int4(e, cols[e], __float_as_int(vals[e]), 0);
        }
    }
}

// ---------------- per-row wave bitonic sort by edge index ----------------
// One wave per row; up to 128 triples held 2-per-lane, exchanges via __shfl_xor.
// Ascending-e order == np.add.at order (keys distinct -> unique sorted result).
__global__ __launch_bounds__(256) void sortrows_kernel(const int* __restrict__ row_ptr,
                                                       int4* __restrict__ tri,
                                                       int2* __restrict__ cpack) {
    int wave = threadIdx.x >> 6;
    int lane = threadIdx.x & 63;
    int row  = blockIdx.x * 4 + wave;
    if (row >= NN) return;
    int beg = row_ptr[row], end = row_ptr[row + 1];
    int deg = end - beg;
    if (deg <= 0) return;

    if (deg <= 128) {
        const int PAD = 0x7fffffff;
        int e0 = PAD, c0 = 0; float v0 = 0.0f;
        int e1 = PAD, c1 = 0; float v1 = 0.0f;
        if (lane < deg) {
            int4 t = tri[beg + lane];
            e0 = t.x; c0 = t.y; v0 = __int_as_float(t.z);
        }
        if (64 + lane < deg) {
            int4 t = tri[beg + 64 + lane];
            e1 = t.x; c1 = t.y; v1 = __int_as_float(t.z);
        }
        #pragma unroll
        for (int k = 2; k <= 128; k <<= 1) {
            #pragma unroll
            for (int j = 64; j > 0; j >>= 1) {
                if (j > (k >> 1)) continue;
                if (j == 64) {
                    if (e0 > e1) {
                        int te = e0; e0 = e1; e1 = te;
                        int tc = c0; c0 = c1; c1 = tc;
                        float tv = v0; v0 = v1; v1 = tv;
                    }
                } else {
                    int   pe = __shfl_xor(e0, j, 64);
                    int   pc = __shfl_xor(c0, j, 64);
                    float pv = __shfl_xor(v0, j, 64);
                    bool tmin0 = ((lane & k) == 0) == ((lane & j) == 0);
                    bool sw0 = tmin0 ? (pe < e0) : (pe > e0);
                    if (sw0) { e0 = pe; c0 = pc; v0 = pv; }
                    int   qe = __shfl_xor(e1, j, 64);
                    int   qc = __shfl_xor(c1, j, 64);
                    float qv = __shfl_xor(v1, j, 64);
                    int i1 = 64 + lane;
                    bool tmin1 = ((i1 & k) == 0) == ((i1 & j) == 0);
                    bool sw1 = tmin1 ? (qe < e1) : (qe > e1);
                    if (sw1) { e1 = qe; c1 = qc; v1 = qv; }
                }
            }
        }
        if (lane < deg)      cpack[beg + lane]      = make_int2(c0, __float_as_int(v0));
        if (64 + lane < deg) cpack[beg + 64 + lane] = make_int2(c1, __float_as_int(v1));
    } else {
        if (lane == 0) {
            for (int i = beg + 1; i < end; ++i) {
                int4 key = tri[i];
                int j = i - 1;
                while (j >= beg && tri[j].x > key.x) { tri[j + 1] = tri[j]; --j; }
                tri[j + 1] = key;
            }
            for (int i = beg; i < end; ++i)
                cpack[i] = make_int2(tri[i].y, tri[i].z);
        }
    }
}

// ---------------- fused SpMM + in-wave npyv norm + noise (+ final combine) ----------------
// One wave per row; lane owns columns [2*lane, 2*lane+1].
// Scalarized edge stream (readfirstlane on beg/end -> s_load edge records,
// SGPR-based gather addressing). Accumulation chain in exact edge order.
// NT: noise NT-load (stream); cpack NORMAL load (re-read 3x -> L3);
// ego stores normal (next layer's gather source); final out NT-store.

template <int LAYER>
__device__ __forceinline__ float2 gather_row(const float* __restrict__ xa,
                                             const float* __restrict__ xb,
                                             int c, int lane) {
    const float* p;
    if (LAYER == 1)
        p = (c < NUM_USERS_) ? (xa + (size_t)c * DD) : (xb + (size_t)(c - NUM_USERS_) * DD);
    else
        p = xa + (size_t)c * DD;
    return ((const float2*)p)[lane];
}

template <int LAYER>   // 1, 2, 3
__global__ __launch_bounds__(256, 2) void layer_kernel(
    const int* __restrict__ row_ptr, const int2* __restrict__ cpack,
    const float* __restrict__ xa,    // L1: user_emb; L2/L3: gather source slab
    const float* __restrict__ xb,    // L1: item_emb; else unused
    const float* __restrict__ noise_k,
    float* __restrict__ y_out,       // L1/L2: ego out slab; L3: final output
    const float* __restrict__ y1,    // L3: ego after layer 1
    const float* __restrict__ y2) {  // L3: ego after layer 2
    int wave = threadIdx.x >> 6;
    int lane = threadIdx.x & 63;
    int row  = blockIdx.x * 4 + wave;
    if (row >= NN) return;

    // wave-uniform row bounds -> SGPR; everything derived is scalar
    int beg = __builtin_amdgcn_readfirstlane(row_ptr[row]);
    int end = __builtin_amdgcn_readfirstlane(row_ptr[row + 1]);

    float a0 = 0.0f, a1 = 0.0f;
    // batches of 32: scalar edge records + 32 independent SGPR-based gathers
    // in flight; accumulate afterwards in exact edge order (masked tail:
    // v=0 -> a+(+/-0)==a bitwise; accumulator can never be -0).
    for (int j = beg; j < end; j += 32) {
        float2 xv[32];
        float  vv[32];
        #pragma unroll
        for (int u = 0; u < 32; ++u) {
            int jj  = j + u;
            int idx = (jj < end) ? jj : (end - 1);   // uniform
            int2 p  = cpack[idx];                    // uniform addr -> s_load
            vv[u] = (jj < end) ? __int_as_float(p.y) : 0.0f;
            xv[u] = gather_row<LAYER>(xa, xb, p.x, lane);
        }
        #pragma unroll
        for (int u = 0; u < 32; ++u) {
            a0 = __fadd_rn(a0, __fmul_rn(vv[u], xv[u].x));
            a1 = __fadd_rn(a1, __fmul_rn(vv[u], xv[u].y));
        }
    }

    // noise row (NT load) + in-wave exact npyv pairwise norm:
    // xor32; xor8; xor16; then halving tree xor4, xor2, xor1; final .x+.y.
    unsigned long long nq = __builtin_nontemporal_load(
        (const unsigned long long*)(noise_k + (long long)row * DD) + lane);
    float2 nv = make_float2(__int_as_float((int)(unsigned)(nq & 0xffffffffull)),
                            __int_as_float((int)(unsigned)(nq >> 32)));
    float sx = __fmul_rn(nv.x, nv.x);
    float sy = __fmul_rn(nv.y, nv.y);
    float tx = __fadd_rn(sx, __shfl_xor(sx, 32, 64));
    float ty = __fadd_rn(sy, __shfl_xor(sy, 32, 64));
    tx = __fadd_rn(tx, __shfl_xor(tx, 8, 64));
    ty = __fadd_rn(ty, __shfl_xor(ty, 8, 64));
    tx = __fadd_rn(tx, __shfl_xor(tx, 16, 64));
    ty = __fadd_rn(ty, __shfl_xor(ty, 16, 64));
    tx = __fadd_rn(tx, __shfl_xor(tx, 4, 64));
    ty = __fadd_rn(ty, __shfl_xor(ty, 4, 64));
    tx = __fadd_rn(tx, __shfl_xor(tx, 2, 64));
    ty = __fadd_rn(ty, __shfl_xor(ty, 2, 64));
    tx = __fadd_rn(tx, __shfl_xor(tx, 1, 64));
    ty = __fadd_rn(ty, __shfl_xor(ty, 1, 64));
    float nrm = __fsqrt_rn(__fadd_rn(tx, ty));

    float s0 = (a0 > 0.0f) ? 1.0f : ((a0 < 0.0f) ? -1.0f : 0.0f);
    float s1 = (a1 > 0.0f) ? 1.0f : ((a1 < 0.0f) ? -1.0f : 0.0f);
    // np order: nk = n / nrm;  t = (sign * nk) * 0.2f;  ego = a + t
    float q0 = __fdiv_rn(nv.x, nrm);
    float q1 = __fdiv_rn(nv.y, nrm);
    float t0 = __fmul_rn(__fmul_rn(s0, q0), 0.2f);
    float t1 = __fmul_rn(__fmul_rn(s1, q1), 0.2f);
    float e0 = __fadd_rn(a0, t0);
    float e1 = __fadd_rn(a1, t1);

    if (LAYER < 3) {
        // normal store: this slab is the next layer's gather source
        ((float2*)(y_out + (long long)row * DD))[lane] = make_float2(e0, e1);
    } else {
        // final = ((e1 + e2) + e3) / 3, identical __fadd_rn/__fdiv_rn chain
        float2 p1 = ((const float2*)(y1 + (long long)row * DD))[lane];
        float2 p2 = ((const float2*)(y2 + (long long)row * DD))[lane];
        float g0 = __fadd_rn(__fadd_rn(p1.x, p2.x), e0);
        float g1 = __fadd_rn(__fadd_rn(p1.y, p2.y), e1);
        float r0 = __fdiv_rn(g0, 3.0f);
        float r1 = __fdiv_rn(g1, 3.0f);
        unsigned long long w =
            ((unsigned long long)(unsigned)__float_as_int(r1) << 32) |
            (unsigned long long)(unsigned)__float_as_int(r0);
        __builtin_nontemporal_store(
            w, (unsigned long long*)(y_out + (long long)row * DD) + lane);
    }
}

extern "C" void kernel_launch(void* const* d_in, const int* in_sizes, int n_in,
                              void* d_out, int out_size, void* d_ws, size_t ws_size,
                              hipStream_t stream) {
    const float* user  = (const float*)d_in[0];
    const float* item  = (const float*)d_in[1];
    const float* vals  = (const float*)d_in[2];
    const float* noise = (const float*)d_in[3];
    const int*   rows  = (const int*)d_in[4];
    const int*   cols  = (const int*)d_in[5];
    float* out = (float*)d_out;

    char* ws = (char*)d_ws;
    size_t off = 0;
    auto alloc = [&](size_t bytes) -> char* {
        char* p = ws + off;
        off = (off + bytes + 255) & ~(size_t)255;
        return p;
    };

    int*   counts  = (int*)  alloc((size_t)NN * 4);
    int*   row_ptr = (int*)  alloc((size_t)(NN + 1) * 4);
    int*   cursor  = (int*)  alloc((size_t)NN * 4);
    int*   bsum    = (int*)  alloc((size_t)NSCANB * 4);
    int*   total   = (int*)  alloc(256);
    int4*  tri     = (int4*) alloc((size_t)NNZ_ * 16);
    int2*  cpack   = (int2*) alloc((size_t)NNZ_ * 8);
    float* ego_a   = (float*)alloc((size_t)NN * DD * 4);
    float* ego_b   = (float*)alloc((size_t)NN * DD * 4);

    hipMemsetAsync(counts, 0, (size_t)NN * 4, stream);

    hist_kernel<<<NSLICE * 8, 256, 0, stream>>>(rows, counts);
    scanA_kernel<<<NSCANB, 256, 0, stream>>>(counts, row_ptr, bsum);
    scanB_kernel<<<1, 256, 0, stream>>>(bsum, total);
    scanC_kernel<<<NSCANB, 256, 0, stream>>>(row_ptr, cursor, bsum, total);
    scatter_kernel<<<NSLICE * 8, 256, 0, stream>>>(rows, cols, vals, cursor, tri);
    sortrows_kernel<<<(NN + 3) / 4, 256, 0, stream>>>(row_ptr, tri, cpack);

    const long long slab = (long long)NN * DD;
    int lgrid = (NN + 3) / 4;
    layer_kernel<1><<<lgrid, 256, 0, stream>>>(row_ptr, cpack, user, item,
                                               noise + 0 * slab, ego_b, nullptr, nullptr);
    layer_kernel<2><<<lgrid, 256, 0, stream>>>(row_ptr, cpack, ego_b, nullptr,
                                               noise + 1 * slab, ego_a, nullptr, nullptr);
    layer_kernel<3><<<lgrid, 256, 0, stream>>>(row_ptr, cpack, ego_a, nullptr,
                                               noise + 2 * slab, out, ego_b, ego_a);
}

// Round 17
// 1561.248 us; speedup vs baseline: 1.0986x; 1.0915x over previous
//
#include <hip/hip_runtime.h>

#define NUM_USERS_ 50000
#define NUM_ITEMS_ 100000
#define NN 150000            // NUM_USERS + NUM_ITEMS
#define DD 128
#define NNZ_ 4800000
#define NLAYERS_ 3
#define SUBR (NN / 8)        // 18750 rows per XCD subrange
#define EPSL 32768           // edges per slice for partitioned hist/scatter
#define NSLICE ((NNZ_ + EPSL - 1) / EPSL)   // 147
#define SCANB 1024           // counts per scan block
#define NSCANB ((NN + SCANB - 1) / SCANB)   // 147

// ---------------- CSR build (deterministic, XCD-partitioned atomics) ----------------
// NOTE (r14 measured): within-row summation ORDER IS LOAD-BEARING. Arbitrary
// order flips a borderline sign (absmax 1.99e-2 vs threshold 6.9e-4). The
// per-row sort by edge index below replicates np.add.at's exact order.

__global__ __launch_bounds__(256) void hist_kernel(const int* __restrict__ rows,
                                                   int* __restrict__ counts) {
    int slice = blockIdx.x >> 3;
    int sub   = blockIdx.x & 7;
    int lo = sub * SUBR, hi = lo + SUBR;
    int base = slice * EPSL;
    int stop = base + EPSL; if (stop > NNZ_) stop = NNZ_;
    for (int e = base + threadIdx.x; e < stop; e += 256) {
        int r = rows[e];
        if (r >= lo && r < hi) atomicAdd(&counts[r], 1);
    }
}

// ---- two-level exclusive scan of counts[0..NN) -> row_ptr / cursor ----
__global__ __launch_bounds__(256) void scanA_kernel(const int* __restrict__ counts,
                                                    int* __restrict__ row_ptr,
                                                    int* __restrict__ bsum) {
    __shared__ int part[256];
    int b = blockIdx.x, t = threadIdx.x;
    int base = b * SCANB + t * 4;
    int c[4];
    #pragma unroll
    for (int u = 0; u < 4; ++u) {
        int i = base + u;
        c[u] = (i < NN) ? counts[i] : 0;
    }
    int mysum = c[0] + c[1] + c[2] + c[3];
    part[t] = mysum;
    __syncthreads();
    for (int off = 1; off < 256; off <<= 1) {
        int v = (t >= off) ? part[t - off] : 0;
        __syncthreads();
        part[t] += v;
        __syncthreads();
    }
    int excl = part[t] - mysum;
    #pragma unroll
    for (int u = 0; u < 4; ++u) {
        int i = base + u;
        if (i < NN) row_ptr[i] = excl;
        excl += c[u];
    }
    if (t == 255) bsum[b] = part[255];
}

__global__ __launch_bounds__(256) void scanB_kernel(int* __restrict__ bsum,
                                                    int* __restrict__ total) {
    __shared__ int s[NSCANB];
    int t = threadIdx.x;
    if (t < NSCANB) s[t] = bsum[t];
    __syncthreads();
    if (t == 0) {
        int run = 0;
        for (int i = 0; i < NSCANB; ++i) {
            int v = s[i];
            s[i] = run;
            run += v;
        }
        *total = run;
    }
    __syncthreads();
    if (t < NSCANB) bsum[t] = s[t];
}

__global__ __launch_bounds__(256) void scanC_kernel(int* __restrict__ row_ptr,
                                                    int* __restrict__ cursor,
                                                    const int* __restrict__ bsum,
                                                    const int* __restrict__ total) {
    int b = blockIdx.x, t = threadIdx.x;
    int off = bsum[b];
    int base = b * SCANB + t * 4;
    #pragma unroll
    for (int u = 0; u < 4; ++u) {
        int i = base + u;
        if (i < NN) {
            int v = row_ptr[i] + off;
            row_ptr[i] = v;
            cursor[i]  = v;
        }
    }
    if (b == 0 && t == 0) row_ptr[NN] = *total;
}

// scatter one packed 16B record (e, col, val, 0) per edge into its CSR slot
// (within-row order arbitrary; fixed by the wave-bitonic sort below).
__global__ __launch_bounds__(256) void scatter_kernel(const int* __restrict__ rows,
                                                      const int* __restrict__ cols,
                                                      const float* __restrict__ vals,
                                                      int* __restrict__ cursor,
                                                      int4* __restrict__ tri) {
    int slice = blockIdx.x >> 3;
    int sub   = blockIdx.x & 7;
    int lo = sub * SUBR, hi = lo + SUBR;
    int base = slice * EPSL;
    int stop = base + EPSL; if (stop > NNZ_) stop = NNZ_;
    for (int e = base + threadIdx.x; e < stop; e += 256) {
        int r = rows[e];
        if (r >= lo && r < hi) {
            int pos = atomicAdd(&cursor[r], 1);
            tri[pos] = make_int4(e, cols[e], __float_as_int(vals[e]), 0);
        }
    }
}

// ---------------- per-row wave bitonic sort by edge index ----------------
// One wave per row. Fast path deg<=64 (1 elem/lane, 21 exchanges); mid path
// deg<=128 (2 elems/lane); serial fallback beyond. Path choice depends only
// on deg -> deterministic; sorted result is the unique ascending-e
// permutation regardless of path (keys distinct).
__global__ __launch_bounds__(256) void sortrows_kernel(const int* __restrict__ row_ptr,
                                                       int4* __restrict__ tri,
                                                       int2* __restrict__ cpack) {
    int wave = threadIdx.x >> 6;
    int lane = threadIdx.x & 63;
    int row  = blockIdx.x * 4 + wave;
    if (row >= NN) return;
    int beg = row_ptr[row], end = row_ptr[row + 1];
    int deg = end - beg;
    if (deg <= 0) return;
    const int PAD = 0x7fffffff;

    if (deg <= 64) {
        // ---- fast path: 1 element/lane, 64-element bitonic via shfl_xor ----
        int e0 = PAD, c0 = 0; float v0 = 0.0f;
        if (lane < deg) {
            int4 t = tri[beg + lane];
            e0 = t.x; c0 = t.y; v0 = __int_as_float(t.z);
        }
        #pragma unroll
        for (int k = 2; k <= 64; k <<= 1) {
            #pragma unroll
            for (int j = 32; j > 0; j >>= 1) {
                if (j > (k >> 1)) continue;
                int   pe = __shfl_xor(e0, j, 64);
                int   pc = __shfl_xor(c0, j, 64);
                float pv = __shfl_xor(v0, j, 64);
                bool tmin = ((lane & k) == 0) == ((lane & j) == 0);
                bool sw = tmin ? (pe < e0) : (pe > e0);
                if (sw) { e0 = pe; c0 = pc; v0 = pv; }
            }
        }
        if (lane < deg) cpack[beg + lane] = make_int2(c0, __float_as_int(v0));
    } else if (deg <= 128) {
        // ---- mid path: 2 elements/lane, 128-element bitonic ----
        int e0 = PAD, c0 = 0; float v0 = 0.0f;
        int e1 = PAD, c1 = 0; float v1 = 0.0f;
        if (lane < deg) {
            int4 t = tri[beg + lane];
            e0 = t.x; c0 = t.y; v0 = __int_as_float(t.z);
        }
        if (64 + lane < deg) {
            int4 t = tri[beg + 64 + lane];
            e1 = t.x; c1 = t.y; v1 = __int_as_float(t.z);
        }
        #pragma unroll
        for (int k = 2; k <= 128; k <<= 1) {
            #pragma unroll
            for (int j = 64; j > 0; j >>= 1) {
                if (j > (k >> 1)) continue;
                if (j == 64) {
                    if (e0 > e1) {
                        int te = e0; e0 = e1; e1 = te;
                        int tc = c0; c0 = c1; c1 = tc;
                        float tv = v0; v0 = v1; v1 = tv;
                    }
                } else {
                    int   pe = __shfl_xor(e0, j, 64);
                    int   pc = __shfl_xor(c0, j, 64);
                    float pv = __shfl_xor(v0, j, 64);
                    bool tmin0 = ((lane & k) == 0) == ((lane & j) == 0);
                    bool sw0 = tmin0 ? (pe < e0) : (pe > e0);
                    if (sw0) { e0 = pe; c0 = pc; v0 = pv; }
                    int   qe = __shfl_xor(e1, j, 64);
                    int   qc = __shfl_xor(c1, j, 64);
                    float qv = __shfl_xor(v1, j, 64);
                    int i1 = 64 + lane;
                    bool tmin1 = ((i1 & k) == 0) == ((i1 & j) == 0);
                    bool sw1 = tmin1 ? (qe < e1) : (qe > e1);
                    if (sw1) { e1 = qe; c1 = qc; v1 = qv; }
                }
            }
        }
        if (lane < deg)      cpack[beg + lane]      = make_int2(c0, __float_as_int(v0));
        if (64 + lane < deg) cpack[beg + 64 + lane] = make_int2(c1, __float_as_int(v1));
    } else {
        if (lane == 0) {
            for (int i = beg + 1; i < end; ++i) {
                int4 key = tri[i];
                int j = i - 1;
                while (j >= beg && tri[j].x > key.x) { tri[j + 1] = tri[j]; --j; }
                tri[j + 1] = key;
            }
            for (int i = beg; i < end; ++i)
                cpack[i] = make_int2(tri[i].y, tri[i].z);
        }
    }
}

// ---------------- fused SpMM + in-wave npyv norm + noise (+ final combine) ----------------
// One wave per row; lane owns columns [2*lane, 2*lane+1].
// Scalarized edge stream (readfirstlane on beg/end -> s_load edge records,
// SGPR-based gather addressing). Accumulation chain in exact edge order.
// NT: noise NT-load (stream); cpack NORMAL load (re-read 3x -> L3);
// ego stores normal (next layer's gather source); final out NT-store.

template <int LAYER>
__device__ __forceinline__ float2 gather_row(const float* __restrict__ xa,
                                             const float* __restrict__ xb,
                                             int c, int lane) {
    const float* p;
    if (LAYER == 1)
        p = (c < NUM_USERS_) ? (xa + (size_t)c * DD) : (xb + (size_t)(c - NUM_USERS_) * DD);
    else
        p = xa + (size_t)c * DD;
    return ((const float2*)p)[lane];
}

template <int LAYER>   // 1, 2, 3
__global__ __launch_bounds__(256, 2) void layer_kernel(
    const int* __restrict__ row_ptr, const int2* __restrict__ cpack,
    const float* __restrict__ xa,    // L1: user_emb; L2/L3: gather source slab
    const float* __restrict__ xb,    // L1: item_emb; else unused
    const float* __restrict__ noise_k,
    float* __restrict__ y_out,       // L1/L2: ego out slab; L3: final output
    const float* __restrict__ y1,    // L3: ego after layer 1
    const float* __restrict__ y2) {  // L3: ego after layer 2
    int wave = threadIdx.x >> 6;
    int lane = threadIdx.x & 63;
    int row  = blockIdx.x * 4 + wave;
    if (row >= NN) return;

    // wave-uniform row bounds -> SGPR; everything derived is scalar
    int beg = __builtin_amdgcn_readfirstlane(row_ptr[row]);
    int end = __builtin_amdgcn_readfirstlane(row_ptr[row + 1]);

    float a0 = 0.0f, a1 = 0.0f;
    // batches of 32: scalar edge records + 32 independent SGPR-based gathers
    // in flight; accumulate afterwards in exact edge order (masked tail:
    // v=0 -> a+(+/-0)==a bitwise; accumulator can never be -0).
    for (int j = beg; j < end; j += 32) {
        float2 xv[32];
        float  vv[32];
        #pragma unroll
        for (int u = 0; u < 32; ++u) {
            int jj  = j + u;
            int idx = (jj < end) ? jj : (end - 1);   // uniform
            int2 p  = cpack[idx];                    // uniform addr -> s_load
            vv[u] = (jj < end) ? __int_as_float(p.y) : 0.0f;
            xv[u] = gather_row<LAYER>(xa, xb, p.x, lane);
        }
        #pragma unroll
        for (int u = 0; u < 32; ++u) {
            a0 = __fadd_rn(a0, __fmul_rn(vv[u], xv[u].x));
            a1 = __fadd_rn(a1, __fmul_rn(vv[u], xv[u].y));
        }
    }

    // noise row (NT load) + in-wave exact npyv pairwise norm:
    // xor32; xor8; xor16; then halving tree xor4, xor2, xor1; final .x+.y.
    unsigned long long nq = __builtin_nontemporal_load(
        (const unsigned long long*)(noise_k + (long long)row * DD) + lane);
    float2 nv = make_float2(__int_as_float((int)(unsigned)(nq & 0xffffffffull)),
                            __int_as_float((int)(unsigned)(nq >> 32)));
    float sx = __fmul_rn(nv.x, nv.x);
    float sy = __fmul_rn(nv.y, nv.y);
    float tx = __fadd_rn(sx, __shfl_xor(sx, 32, 64));
    float ty = __fadd_rn(sy, __shfl_xor(sy, 32, 64));
    tx = __fadd_rn(tx, __shfl_xor(tx, 8, 64));
    ty = __fadd_rn(ty, __shfl_xor(ty, 8, 64));
    tx = __fadd_rn(tx, __shfl_xor(tx, 16, 64));
    ty = __fadd_rn(ty, __shfl_xor(ty, 16, 64));
    tx = __fadd_rn(tx, __shfl_xor(tx, 4, 64));
    ty = __fadd_rn(ty, __shfl_xor(ty, 4, 64));
    tx = __fadd_rn(tx, __shfl_xor(tx, 2, 64));
    ty = __fadd_rn(ty, __shfl_xor(ty, 2, 64));
    tx = __fadd_rn(tx, __shfl_xor(tx, 1, 64));
    ty = __fadd_rn(ty, __shfl_xor(ty, 1, 64));
    float nrm = __fsqrt_rn(__fadd_rn(tx, ty));

    float s0 = (a0 > 0.0f) ? 1.0f : ((a0 < 0.0f) ? -1.0f : 0.0f);
    float s1 = (a1 > 0.0f) ? 1.0f : ((a1 < 0.0f) ? -1.0f : 0.0f);
    // np order: nk = n / nrm;  t = (sign * nk) * 0.2f;  ego = a + t
    float q0 = __fdiv_rn(nv.x, nrm);
    float q1 = __fdiv_rn(nv.y, nrm);
    float t0 = __fmul_rn(__fmul_rn(s0, q0), 0.2f);
    float t1 = __fmul_rn(__fmul_rn(s1, q1), 0.2f);
    float e0 = __fadd_rn(a0, t0);
    float e1 = __fadd_rn(a1, t1);

    if (LAYER < 3) {
        // normal store: this slab is the next layer's gather source
        ((float2*)(y_out + (long long)row * DD))[lane] = make_float2(e0, e1);
    } else {
        // final = ((e1 + e2) + e3) / 3, identical __fadd_rn/__fdiv_rn chain
        float2 p1 = ((const float2*)(y1 + (long long)row * DD))[lane];
        float2 p2 = ((const float2*)(y2 + (long long)row * DD))[lane];
        float g0 = __fadd_rn(__fadd_rn(p1.x, p2.x), e0);
        float g1 = __fadd_rn(__fadd_rn(p1.y, p2.y), e1);
        float r0 = __fdiv_rn(g0, 3.0f);
        float r1 = __fdiv_rn(g1, 3.0f);
        unsigned long long w =
            ((unsigned long long)(unsigned)__float_as_int(r1) << 32) |
            (unsigned long long)(unsigned)__float_as_int(r0);
        __builtin_nontemporal_store(
            w, (unsigned long long*)(y_out + (long long)row * DD) + lane);
    }
}

extern "C" void kernel_launch(void* const* d_in, const int* in_sizes, int n_in,
                              void* d_out, int out_size, void* d_ws, size_t ws_size,
                              hipStream_t stream) {
    const float* user  = (const float*)d_in[0];
    const float* item  = (const float*)d_in[1];
    const float* vals  = (const float*)d_in[2];
    const float* noise = (const float*)d_in[3];
    const int*   rows  = (const int*)d_in[4];
    const int*   cols  = (const int*)d_in[5];
    float* out = (float*)d_out;

    char* ws = (char*)d_ws;
    size_t off = 0;
    auto alloc = [&](size_t bytes) -> char* {
        char* p = ws + off;
        off = (off + bytes + 255) & ~(size_t)255;
        return p;
    };

    int*   counts  = (int*)  alloc((size_t)NN * 4);
    int*   row_ptr = (int*)  alloc((size_t)(NN + 1) * 4);
    int*   cursor  = (int*)  alloc((size_t)NN * 4);
    int*   bsum    = (int*)  alloc((size_t)NSCANB * 4);
    int*   total   = (int*)  alloc(256);
    int4*  tri     = (int4*) alloc((size_t)NNZ_ * 16);
    int2*  cpack   = (int2*) alloc((size_t)NNZ_ * 8);
    float* ego_a   = (float*)alloc((size_t)NN * DD * 4);
    float* ego_b   = (float*)alloc((size_t)NN * DD * 4);

    hipMemsetAsync(counts, 0, (size_t)NN * 4, stream);

    hist_kernel<<<NSLICE * 8, 256, 0, stream>>>(rows, counts);
    scanA_kernel<<<NSCANB, 256, 0, stream>>>(counts, row_ptr, bsum);
    scanB_kernel<<<1, 256, 0, stream>>>(bsum, total);
    scanC_kernel<<<NSCANB, 256, 0, stream>>>(row_ptr, cursor, bsum, total);
    scatter_kernel<<<NSLICE * 8, 256, 0, stream>>>(rows, cols, vals, cursor, tri);
    sortrows_kernel<<<(NN + 3) / 4, 256, 0, stream>>>(row_ptr, tri, cpack);

    const long long slab = (long long)NN * DD;
    int lgrid = (NN + 3) / 4;
    layer_kernel<1><<<lgrid, 256, 0, stream>>>(row_ptr, cpack, user, item,
                                               noise + 0 * slab, ego_b, nullptr, nullptr);
    layer_kernel<2><<<lgrid, 256, 0, stream>>>(row_ptr, cpack, ego_b, nullptr,
                                               noise + 1 * slab, ego_a, nullptr, nullptr);
    layer_kernel<3><<<lgrid, 256, 0, stream>>>(row_ptr, cpack, ego_a, nullptr,
                                               noise + 2 * slab, out, ego_b, ego_a);
}